// Round 2
// baseline (1202.407 us; speedup 1.0000x reference)
//
#include <hip/hip_runtime.h>

typedef unsigned short ushort_t;
typedef __attribute__((ext_vector_type(8))) short short8;
typedef __attribute__((ext_vector_type(8))) unsigned short ushort8;
typedef __attribute__((ext_vector_type(4))) unsigned short ushort4v;
typedef __attribute__((ext_vector_type(4))) float floatx4;
typedef __attribute__((ext_vector_type(4))) unsigned int uint4v;

static __device__ __forceinline__ ushort_t f2b(float f) {
    unsigned int x;
    __builtin_memcpy(&x, &f, 4);
    x += 0x7fffu + ((x >> 16) & 1u);   // round-to-nearest-even
    return (ushort_t)(x >> 16);
}
static __device__ __forceinline__ float b2f(ushort_t u) {
    unsigned int x = ((unsigned int)u) << 16;
    float f;
    __builtin_memcpy(&f, &x, 4);
    return f;
}

// load 8 consecutive elements as bf16x8 (converting if source is f32)
static __device__ __forceinline__ ushort8 ld8bf(const float* p) {
    const floatx4* q = (const floatx4*)p;
    floatx4 a = q[0], b = q[1];
    ushort8 r;
    r[0] = f2b(a[0]); r[1] = f2b(a[1]); r[2] = f2b(a[2]); r[3] = f2b(a[3]);
    r[4] = f2b(b[0]); r[5] = f2b(b[1]); r[6] = f2b(b[2]); r[7] = f2b(b[3]);
    return r;
}
static __device__ __forceinline__ ushort8 ld8bf(const ushort_t* p) {
    return *(const ushort8*)p;
}
static __device__ __forceinline__ void stc(float* C, long long idx, float v) { C[idx] = v; }
static __device__ __forceinline__ void stc(ushort_t* C, long long idx, float v) { C[idx] = f2b(v); }

// ---------------------------------------------------------------------------
// NT GEMM: C[m,n] = alpha * (sum_k A[m,k]*B[n,k]) + bias[n]
// A:(M,K) lda, B:(N,K) ldb (both f32 or bf16), C:(M,N) ldc (f32 or bf16).
// MFMA in bf16, f32 accumulate. Batched via blockIdx.z.
// Block 256 thr = 4 waves; tile 128x128, BK=32; wave = 64x64 (4x4 MFMA tiles).
// ---------------------------------------------------------------------------
template <typename TA, typename TB, typename TC>
__global__ __launch_bounds__(256) void gemm_nt_kernel(
    const TA* __restrict__ A, const TB* __restrict__ Bm,
    const float* __restrict__ bias, TC* __restrict__ C,
    int K, int lda, int ldb, int ldc,
    int innerCnt, long long sAo, long long sAi, long long sBo, long long sBi,
    long long sCo, long long sCi,
    const float* __restrict__ alphaPtr)
{
    __shared__ __align__(16) ushort_t sA[128][40];  // +8 pad: 2-way alias only (free)
    __shared__ __align__(16) ushort_t sB[128][40];

    const int z = blockIdx.z;
    const int zo = z / innerCnt, zi = z % innerCnt;
    A  += (long long)zo * sAo + (long long)zi * sAi;
    Bm += (long long)zo * sBo + (long long)zi * sBi;
    C  += (long long)zo * sCo + (long long)zi * sCi;

    const int m0 = blockIdx.y * 128;
    const int n0 = blockIdx.x * 128;
    const int t = threadIdx.x;
    const int lane = t & 63;
    const int wave = t >> 6;
    const int wm = (wave >> 1) * 64;
    const int wn = (wave & 1) * 64;
    const int lr = lane & 15;
    const int lk = (lane >> 4) * 8;
    const int lq = (lane >> 4) * 4;

    floatx4 acc[4][4];
    #pragma unroll
    for (int i = 0; i < 4; ++i)
        #pragma unroll
        for (int j = 0; j < 4; ++j)
            acc[i][j] = (floatx4){0.f, 0.f, 0.f, 0.f};

    const int r0 = t >> 2;          // staging row 0..63
    const int c0 = (t & 3) * 8;     // staging col {0,8,16,24}

    for (int k0 = 0; k0 < K; k0 += 32) {
        ushort8 va0 = ld8bf(A  + (long long)(m0 + r0)      * lda + (k0 + c0));
        ushort8 va1 = ld8bf(A  + (long long)(m0 + 64 + r0) * lda + (k0 + c0));
        ushort8 vb0 = ld8bf(Bm + (long long)(n0 + r0)      * ldb + (k0 + c0));
        ushort8 vb1 = ld8bf(Bm + (long long)(n0 + 64 + r0) * ldb + (k0 + c0));
        *(ushort8*)(&sA[r0][c0])      = va0;
        *(ushort8*)(&sA[64 + r0][c0]) = va1;
        *(ushort8*)(&sB[r0][c0])      = vb0;
        *(ushort8*)(&sB[64 + r0][c0]) = vb1;
        __syncthreads();

        short8 af[4], bf[4];
        #pragma unroll
        for (int mi = 0; mi < 4; ++mi)
            af[mi] = *(const short8*)(&sA[wm + mi * 16 + lr][lk]);
        #pragma unroll
        for (int ni = 0; ni < 4; ++ni)
            bf[ni] = *(const short8*)(&sB[wn + ni * 16 + lr][lk]);
        #pragma unroll
        for (int mi = 0; mi < 4; ++mi)
            #pragma unroll
            for (int ni = 0; ni < 4; ++ni)
                acc[mi][ni] = __builtin_amdgcn_mfma_f32_16x16x32_bf16(
                    af[mi], bf[ni], acc[mi][ni], 0, 0, 0);
        __syncthreads();
    }

    const float alpha = alphaPtr ? *alphaPtr : 1.0f;

    #pragma unroll
    for (int mi = 0; mi < 4; ++mi) {
        #pragma unroll
        for (int ni = 0; ni < 4; ++ni) {
            const int col = n0 + wn + ni * 16 + lr;
            const float bv = bias ? bias[col] : 0.0f;
            #pragma unroll
            for (int r = 0; r < 4; ++r) {
                const int row = m0 + wm + mi * 16 + lq + r;
                stc(C, (long long)row * ldc + col, acc[mi][ni][r] * alpha + bv);
            }
        }
    }
}

// ---------------------------------------------------------------------------
// NN GEMM, N fixed 64: C[m,n] = sum_k A[m,k]*B[k,n]
// A: f32 (M,K) lda; B: bf16 (K,64) ldb; C: bf16 (M,64) ldc. B transposed in LDS.
// Block 256 thr = 4 waves; tile 128(M)x64(N), BK=32; wave = 32x64 (2x4 tiles).
// ---------------------------------------------------------------------------
__global__ __launch_bounds__(256) void gemm_nn64_kernel(
    const float* __restrict__ A, const ushort_t* __restrict__ Bm,
    ushort_t* __restrict__ C,
    int K, int lda, int ldb, int ldc,
    int innerCnt, long long sAo, long long sAi, long long sBo, long long sBi,
    long long sCo, long long sCi)
{
    __shared__ __align__(16) ushort_t sA[128][40];
    __shared__ __align__(16) ushort_t sBt[64][40];   // [n][k]

    const int z = blockIdx.z;
    const int zo = z / innerCnt, zi = z % innerCnt;
    A  += (long long)zo * sAo + (long long)zi * sAi;
    Bm += (long long)zo * sBo + (long long)zi * sBi;
    C  += (long long)zo * sCo + (long long)zi * sCi;

    const int m0 = blockIdx.x * 128;
    const int t = threadIdx.x;
    const int lane = t & 63;
    const int wave = t >> 6;
    const int lr = lane & 15;
    const int lk = (lane >> 4) * 8;
    const int lq = (lane >> 4) * 4;
    const int r0 = t >> 2;
    const int c0 = (t & 3) * 8;
    const int kk = t >> 3;          // 0..31
    const int nc = (t & 7) * 8;     // 0..56

    floatx4 acc[2][4];
    #pragma unroll
    for (int i = 0; i < 2; ++i)
        #pragma unroll
        for (int j = 0; j < 4; ++j)
            acc[i][j] = (floatx4){0.f, 0.f, 0.f, 0.f};

    for (int k0 = 0; k0 < K; k0 += 32) {
        ushort8 va0 = ld8bf(A + (long long)(m0 + r0)      * lda + (k0 + c0));
        ushort8 va1 = ld8bf(A + (long long)(m0 + 64 + r0) * lda + (k0 + c0));
        ushort8 vb = *(const ushort8*)(Bm + (long long)(k0 + kk) * ldb + nc);
        *(ushort8*)(&sA[r0][c0])      = va0;
        *(ushort8*)(&sA[64 + r0][c0]) = va1;
        #pragma unroll
        for (int j = 0; j < 8; ++j) sBt[nc + j][kk] = vb[j];
        __syncthreads();

        short8 af[2], bf[4];
        #pragma unroll
        for (int mi = 0; mi < 2; ++mi)
            af[mi] = *(const short8*)(&sA[wave * 32 + mi * 16 + lr][lk]);
        #pragma unroll
        for (int ni = 0; ni < 4; ++ni)
            bf[ni] = *(const short8*)(&sBt[ni * 16 + lr][lk]);
        #pragma unroll
        for (int mi = 0; mi < 2; ++mi)
            #pragma unroll
            for (int ni = 0; ni < 4; ++ni)
                acc[mi][ni] = __builtin_amdgcn_mfma_f32_16x16x32_bf16(
                    af[mi], bf[ni], acc[mi][ni], 0, 0, 0);
        __syncthreads();
    }

    #pragma unroll
    for (int mi = 0; mi < 2; ++mi) {
        #pragma unroll
        for (int ni = 0; ni < 4; ++ni) {
            const int col = ni * 16 + lr;
            #pragma unroll
            for (int r = 0; r < 4; ++r) {
                const int row = m0 + wave * 32 + mi * 16 + lq + r;
                C[(long long)row * ldc + col] = f2b(acc[mi][ni][r]);
            }
        }
    }
}

// ---------------------------------------------------------------------------
// In-place f32 softmax over rows of 2048. One block (256 thr) per row.
// ---------------------------------------------------------------------------
__global__ __launch_bounds__(256) void softmax_kernel(float* __restrict__ attn)
{
    const long long row = blockIdx.x;
    float* p = attn + row * 2048;
    const int t = threadIdx.x;

    floatx4 v0 = *(const floatx4*)(p + t * 8);
    floatx4 v1 = *(const floatx4*)(p + t * 8 + 4);
    float x[8];
    #pragma unroll
    for (int j = 0; j < 4; ++j) { x[j] = v0[j]; x[4 + j] = v1[j]; }

    float m = x[0];
    #pragma unroll
    for (int j = 1; j < 8; ++j) m = fmaxf(m, x[j]);
    #pragma unroll
    for (int o = 32; o > 0; o >>= 1) m = fmaxf(m, __shfl_xor(m, o, 64));

    __shared__ float redm[4], reds[4];
    if ((t & 63) == 0) redm[t >> 6] = m;
    __syncthreads();
    m = fmaxf(fmaxf(redm[0], redm[1]), fmaxf(redm[2], redm[3]));

    float s = 0.f;
    #pragma unroll
    for (int j = 0; j < 8; ++j) { x[j] = __expf(x[j] - m); s += x[j]; }
    #pragma unroll
    for (int o = 32; o > 0; o >>= 1) s += __shfl_xor(s, o, 64);
    if ((t & 63) == 0) reds[t >> 6] = s;
    __syncthreads();
    s = reds[0] + reds[1] + reds[2] + reds[3];

    const float inv = 1.0f / s;
    floatx4 w0, w1;
    #pragma unroll
    for (int j = 0; j < 4; ++j) { w0[j] = x[j] * inv; w1[j] = x[4 + j] * inv; }
    *(floatx4*)(p + t * 8) = w0;
    *(floatx4*)(p + t * 8 + 4) = w1;
}

// ---------------------------------------------------------------------------
// LayerNorm(proj(bf16) + resid(f32)) * gamma + beta -> f32. Rows of 1024.
// ---------------------------------------------------------------------------
__global__ __launch_bounds__(256) void ln_kernel(
    const ushort_t* __restrict__ proj, const float* __restrict__ resid,
    const float* __restrict__ gamma, const float* __restrict__ beta,
    float* __restrict__ out)
{
    const int row = blockIdx.x;
    const int t = threadIdx.x;
    const long long base = (long long)row * 1024 + t * 4;

    ushort4v vp = *(const ushort4v*)(proj + base);
    floatx4 vr = *(const floatx4*)(resid + base);
    float x[4];
    #pragma unroll
    for (int j = 0; j < 4; ++j) x[j] = b2f(vp[j]) + vr[j];

    __shared__ float red1[4], red2[4];
    float s = x[0] + x[1] + x[2] + x[3];
    #pragma unroll
    for (int o = 32; o > 0; o >>= 1) s += __shfl_xor(s, o, 64);
    if ((t & 63) == 0) red1[t >> 6] = s;
    __syncthreads();
    s = red1[0] + red1[1] + red1[2] + red1[3];
    const float mu = s * (1.0f / 1024.0f);

    float ss = 0.f;
    #pragma unroll
    for (int j = 0; j < 4; ++j) { const float d = x[j] - mu; ss += d * d; }
    #pragma unroll
    for (int o = 32; o > 0; o >>= 1) ss += __shfl_xor(ss, o, 64);
    if ((t & 63) == 0) red2[t >> 6] = ss;
    __syncthreads();
    ss = red2[0] + red2[1] + red2[2] + red2[3];
    const float rstd = rsqrtf(ss * (1.0f / 1024.0f) + 1e-5f);

    floatx4 g = *(const floatx4*)(gamma + t * 4);
    floatx4 b = *(const floatx4*)(beta + t * 4);
    floatx4 o;
    #pragma unroll
    for (int j = 0; j < 4; ++j)
        o[j] = (x[j] - mu) * rstd * g[j] + b[j];
    *(floatx4*)(out + base) = o;
}

// ---------------------------------------------------------------------------
extern "C" void kernel_launch(void* const* d_in, const int* in_sizes, int n_in,
                              void* d_out, int out_size, void* d_ws, size_t ws_size,
                              hipStream_t stream)
{
    const float* query = (const float*)d_in[0];
    const float* key_  = (const float*)d_in[1];
    const float* value = (const float*)d_in[2];
    const float* Wq = (const float*)d_in[3];
    const float* bq = (const float*)d_in[4];
    const float* Wk = (const float*)d_in[5];
    const float* bk = (const float*)d_in[6];
    const float* Wv = (const float*)d_in[7];
    const float* bv = (const float*)d_in[8];
    const float* Wo = (const float*)d_in[9];
    const float* bo = (const float*)d_in[10];
    const float* gamma = (const float*)d_in[11];
    const float* beta  = (const float*)d_in[12];
    const float* temp  = (const float*)d_in[13];

    float* out    = (float*)d_out;
    float* ln_out = out;                               // [2,2048,1024] f32
    float* attn   = out + (long long)4096 * 1024;      // [2,16,2048,2048] f32

    // ws (bf16 intermediates): Qb,Kb,Vb 8MB each; Cx reuses Qb, Pj reuses Kb
    ushort_t* Qb = (ushort_t*)d_ws;
    ushort_t* Kb = Qb + 4194304;
    ushort_t* Vb = Kb + 4194304;
    ushort_t* Cx = Qb;
    ushort_t* Pj = Kb;

    const dim3 blk(256, 1, 1);

    // Q/K/V projections: [4096,1024] = in @ W^T + b   (f32 in -> bf16 out)
    gemm_nt_kernel<float, float, ushort_t><<<dim3(8, 32, 1), blk, 0, stream>>>(
        query, Wq, bq, Qb, 1024, 1024, 1024, 1024,
        1, 0LL, 0LL, 0LL, 0LL, 0LL, 0LL, nullptr);
    gemm_nt_kernel<float, float, ushort_t><<<dim3(8, 32, 1), blk, 0, stream>>>(
        key_, Wk, bk, Kb, 1024, 1024, 1024, 1024,
        1, 0LL, 0LL, 0LL, 0LL, 0LL, 0LL, nullptr);
    gemm_nt_kernel<float, float, ushort_t><<<dim3(8, 32, 1), blk, 0, stream>>>(
        value, Wv, bv, Vb, 1024, 1024, 1024, 1024,
        1, 0LL, 0LL, 0LL, 0LL, 0LL, 0LL, nullptr);

    // scores[b,h,q,k] = temp * Q[b,q,h,:] . K[b,k,h,:]  (32 batches, K=64) -> f32
    gemm_nt_kernel<ushort_t, ushort_t, float><<<dim3(16, 16, 32), blk, 0, stream>>>(
        Qb, Kb, nullptr, attn, 64, 1024, 1024, 2048,
        16, 2097152LL, 64LL, 2097152LL, 64LL, 67108864LL, 4194304LL, temp);

    // softmax in-place (f32), 65536 rows
    softmax_kernel<<<dim3(65536, 1, 1), blk, 0, stream>>>(attn);

    // context[b,q,h,:] = P[b,h,q,:] @ V[b,:,h,:]  (f32 P -> bf16 ctx)
    gemm_nn64_kernel<<<dim3(16, 1, 32), blk, 0, stream>>>(
        attn, Vb, Cx, 2048, 2048, 1024, 1024,
        16, 67108864LL, 4194304LL, 2097152LL, 64LL, 2097152LL, 64LL);

    // output projection: bf16 ctx x f32 Wo -> bf16 proj
    gemm_nt_kernel<ushort_t, float, ushort_t><<<dim3(8, 32, 1), blk, 0, stream>>>(
        Cx, Wo, bo, Pj, 1024, 1024, 1024, 1024,
        1, 0LL, 0LL, 0LL, 0LL, 0LL, 0LL, nullptr);

    // residual + layernorm -> f32
    ln_kernel<<<dim3(4096, 1, 1), blk, 0, stream>>>(Pj, query, gamma, beta, ln_out);
}